// Round 11
// baseline (31.122 us; speedup 1.0000x reference)
//
#include <hip/hip_runtime.h>
#include <math.h>

#define BB 16
#define PP 2048
#define EPSF 1e-8f
#define SCALE (1.0f / (BB * PP))
#define NCHUNK 32   // 32 col-chunks of 64 cols
#define RPT 8       // rows per thread per dispatch (row-split: 2 dispatches)

typedef float f2 __attribute__((ext_vector_type(2)));

// packed fp32 fma: d = a*b + c on both 32-bit halves (gfx90a+/gfx950 VOP3P)
static __device__ __forceinline__ f2 pkfma(f2 a, f2 b, f2 c) {
  f2 d;
  asm("v_pk_fma_f32 %0, %1, %2, %3" : "=v"(d) : "v"(a), "v"(b), "v"(c));
  return d;
}

// ---------------- Kernel P: fused transform + pairwise partial min ----------
// R9 structure (best measured), rows split across two dispatches.
// grid = 512: blk = db(5b)*16 + sc(4b). block = 256 = two halves of 128 thr.
// Half h covers col-chunk cc = sc*2+h (64 cols); rows rowbase..rowbase+1023,
// 8 rows/thread. Inner: packed rows/cols + diagonal trick (6 pk_fma + 2 min3
// per 2x2 block). partial layout: partial[cc][db][row] (32x32x2048 = 8 MB)
__global__ __launch_bounds__(256) void pairtrans_kernel(
    const float* __restrict__ R_t, const float* __restrict__ t_t,
    const float* __restrict__ R_p, const float* __restrict__ t_p,
    const float* __restrict__ mp,
    float* __restrict__ partial, float* __restrict__ out, int rowbase) {
  __shared__ f2 Qx[2][32], Qy[2][32], Qz[2][32], Qw[2][32];  // 2 KB
  int blk = blockIdx.x;
  int t = threadIdx.x;
  if (rowbase == 0 && blk == 0 && t == 0) *out = 0.0f;  // finish runs after
  int sc = blk & 15;
  int db = blk >> 4;  // 0..31
  int dir = db & 1;
  int b = db >> 1;
  int h = t >> 7;        // half 0/1
  int tl = t & 127;
  int cc = (sc << 1) | h;  // col chunk 0..31
  const float* Rr = (dir ? R_p : R_t) + b * 9;
  const float* tr_ = (dir ? t_p : t_t) + b * 3;
  const float* Rc = (dir ? R_t : R_p) + b * 9;
  const float* tc_ = (dir ? t_t : t_p) + b * 3;

  // --- transform 64 cols of this half -> LDS (col form: -2q, |q|^2) ---
  if (tl < 64) {
    int ci = (b << 11) + (cc << 6) + tl;
    float x = mp[ci * 3], y = mp[ci * 3 + 1], z = mp[ci * 3 + 2];
    float qx = fmaf(Rc[0], x, fmaf(Rc[1], y, fmaf(Rc[2], z, tc_[0])));
    float qy = fmaf(Rc[3], x, fmaf(Rc[4], y, fmaf(Rc[5], z, tc_[1])));
    float qz = fmaf(Rc[6], x, fmaf(Rc[7], y, fmaf(Rc[8], z, tc_[2])));
    float qw = fmaf(qx, qx, fmaf(qy, qy, qz * qz));
    ((float*)&Qx[h][0])[tl] = -2.f * qx;
    ((float*)&Qy[h][0])[tl] = -2.f * qy;
    ((float*)&Qz[h][0])[tl] = -2.f * qz;
    ((float*)&Qw[h][0])[tl] = qw;
  }

  // --- transform this thread's 8 rows -> packed row-pair registers ---
  float r0 = Rr[0], r1 = Rr[1], r2 = Rr[2], r3 = Rr[3], r4 = Rr[4],
        r5 = Rr[5], r6 = Rr[6], r7 = Rr[7], r8 = Rr[8];
  float t0 = tr_[0], t1 = tr_[1], t2 = tr_[2];
  f2 ax[RPT / 2], ay[RPT / 2], az[RPT / 2], aw[RPT / 2];
#pragma unroll
  for (int k = 0; k < RPT; ++k) {
    int ri = (b << 11) + rowbase + (k << 7) + tl;
    float x = mp[ri * 3], y = mp[ri * 3 + 1], z = mp[ri * 3 + 2];
    float px = fmaf(r0, x, fmaf(r1, y, fmaf(r2, z, t0)));
    float py = fmaf(r3, x, fmaf(r4, y, fmaf(r5, z, t1)));
    float pz = fmaf(r6, x, fmaf(r7, y, fmaf(r8, z, t2)));
    float pw = fmaf(px, px, fmaf(py, py, pz * pz));
    if (k & 1) {
      ax[k >> 1].y = px; ay[k >> 1].y = py; az[k >> 1].y = pz; aw[k >> 1].y = pw;
    } else {
      ax[k >> 1].x = px; ay[k >> 1].x = py; az[k >> 1].x = pz; aw[k >> 1].x = pw;
    }
  }
  __syncthreads();

  float m[RPT];
#pragma unroll
  for (int k = 0; k < RPT; ++k) m[k] = 3.0e38f;

  const f2* qx = &Qx[h][0];
  const f2* qy = &Qy[h][0];
  const f2* qz = &Qz[h][0];
  const f2* qw = &Qw[h][0];

#pragma unroll 2
  for (int jp = 0; jp < 32; ++jp) {
    f2 X = qx[jp], Y = qy[jp], Z = qz[jp], W = qw[jp];
    f2 Xs, Ys, Zs, Ws;
    Xs.x = X.y; Xs.y = X.x;
    Ys.x = Y.y; Ys.y = Y.x;
    Zs.x = Z.y; Zs.y = Z.x;
    Ws.x = W.y; Ws.y = W.x;
#pragma unroll
    for (int kk = 0; kk < RPT / 2; ++kk) {
      f2 d1 = pkfma(ax[kk], X, pkfma(ay[kk], Y, pkfma(az[kk], Z, W)));
      f2 d2 = pkfma(ax[kk], Xs, pkfma(ay[kk], Ys, pkfma(az[kk], Zs, Ws)));
      m[2 * kk]     = fminf(fminf(m[2 * kk], d1.x), d2.x);      // v_min3
      m[2 * kk + 1] = fminf(fminf(m[2 * kk + 1], d1.y), d2.y);  // v_min3
    }
  }

  float* pp = partial + (cc << 16) + (db << 11) + rowbase + tl;
#pragma unroll
  for (int kk = 0; kk < RPT / 2; ++kk) {
    pp[(2 * kk) << 7]     = m[2 * kk] + aw[kk].x;
    pp[(2 * kk + 1) << 7] = m[2 * kk + 1] + aw[kk].y;
  }
}

// ---------------- Kernel F: reduce chunks + sqrt + mean ----------------
__global__ __launch_bounds__(256) void finish_kernel(
    const float* __restrict__ partial, float* __restrict__ out) {
  int idx = blockIdx.x * 256 + threadIdx.x;  // 0..65535 = db*2048+row
  float v = partial[idx];
#pragma unroll
  for (int c = 1; c < NCHUNK; ++c) v = fminf(v, partial[(c << 16) + idx]);
  v = fmaxf(v, 0.0f);  // guard tiny negative from cancellation
  float s = sqrtf(v + EPSF) * SCALE;
  for (int off = 32; off; off >>= 1) s += __shfl_down(s, off, 64);
  __shared__ float wsum[4];
  if ((threadIdx.x & 63) == 0) wsum[threadIdx.x >> 6] = s;
  __syncthreads();
  if (threadIdx.x == 0) atomicAdd(out, wsum[0] + wsum[1] + wsum[2] + wsum[3]);
}

// ---------------- Fallback (tiny ws): self-contained, no scratch ------------
__global__ __launch_bounds__(256) void fallback_kernel(
    const float* __restrict__ R_t, const float* __restrict__ t_t,
    const float* __restrict__ R_p, const float* __restrict__ t_p,
    const float* __restrict__ mp, float* __restrict__ out) {
  __shared__ float4 lds[PP];  // 32 KB
  int blk = blockIdx.x;
  int rc  = blk & 7;
  int dir = (blk >> 3) & 1;
  int b   = blk >> 4;
  const float* Rr = (dir ? R_p : R_t) + b * 9;
  const float* tr_ = (dir ? t_p : t_t) + b * 3;
  const float* Rc = (dir ? R_t : R_p) + b * 9;
  const float* tcp = (dir ? t_t : t_p) + b * 3;
  float c0 = Rc[0], c1 = Rc[1], c2 = Rc[2], c3 = Rc[3], c4 = Rc[4],
        c5 = Rc[5], c6 = Rc[6], c7 = Rc[7], c8 = Rc[8];
  float tc0 = tcp[0], tc1 = tcp[1], tc2 = tcp[2];
  for (int j = threadIdx.x; j < PP; j += 256) {
    int gi = (b * PP + j) * 3;
    float x = mp[gi], y = mp[gi + 1], z = mp[gi + 2];
    float4 q;
    q.x = fmaf(c0, x, fmaf(c1, y, fmaf(c2, z, tc0)));
    q.y = fmaf(c3, x, fmaf(c4, y, fmaf(c5, z, tc1)));
    q.z = fmaf(c6, x, fmaf(c7, y, fmaf(c8, z, tc2)));
    q.w = 0.f;
    lds[j] = q;
  }
  __syncthreads();
  int row = rc * 256 + threadIdx.x;
  int gi = (b * PP + row) * 3;
  float x = mp[gi], y = mp[gi + 1], z = mp[gi + 2];
  float ax = fmaf(Rr[0], x, fmaf(Rr[1], y, fmaf(Rr[2], z, tr_[0])));
  float ay = fmaf(Rr[3], x, fmaf(Rr[4], y, fmaf(Rr[5], z, tr_[1])));
  float az = fmaf(Rr[6], x, fmaf(Rr[7], y, fmaf(Rr[8], z, tr_[2])));
  float m = 3.4e38f;
#pragma unroll 8
  for (int j = 0; j < PP; ++j) {
    float4 q = lds[j];
    float dx = ax - q.x, dy = ay - q.y, dz = az - q.z;
    float d = fmaf(dx, dx, fmaf(dy, dy, dz * dz));
    m = fminf(m, d);
  }
  float v = sqrtf(m + EPSF) * SCALE;
  for (int off = 32; off; off >>= 1) v += __shfl_down(v, off, 64);
  __shared__ float wsum[4];
  if ((threadIdx.x & 63) == 0) wsum[threadIdx.x >> 6] = v;
  __syncthreads();
  if (threadIdx.x == 0) atomicAdd(out, wsum[0] + wsum[1] + wsum[2] + wsum[3]);
}

extern "C" void kernel_launch(void* const* d_in, const int* in_sizes, int n_in,
                              void* d_out, int out_size, void* d_ws, size_t ws_size,
                              hipStream_t stream) {
  const float* R_t = (const float*)d_in[0];
  const float* t_t = (const float*)d_in[1];
  const float* R_p = (const float*)d_in[2];
  const float* t_p = (const float*)d_in[3];
  const float* mp  = (const float*)d_in[4];
  float* out = (float*)d_out;

  size_t need = (size_t)NCHUNK * 2 * BB * PP * sizeof(float);  // 8 MB
  if (ws_size >= need) {
    float* partial = (float*)d_ws;
    pairtrans_kernel<<<512, 256, 0, stream>>>(R_t, t_t, R_p, t_p, mp, partial, out, 0);
    pairtrans_kernel<<<512, 256, 0, stream>>>(R_t, t_t, R_p, t_p, mp, partial, out, 1024);
    finish_kernel<<<256, 256, 0, stream>>>(partial, out);
  } else {
    hipMemsetAsync(d_out, 0, sizeof(float), stream);
    fallback_kernel<<<256, 256, 0, stream>>>(R_t, t_t, R_p, t_p, mp, out);
  }
}

// Round 12
// 20.611 us; speedup vs baseline: 1.5099x; 1.5099x over previous
//
#include <hip/hip_runtime.h>
#include <math.h>

#define BB 16
#define PP 2048
#define EPSF 1e-8f
#define SCALE (1.0f / (BB * PP))

typedef _Float16 half8 __attribute__((ext_vector_type(8)));
typedef float floatx16 __attribute__((ext_vector_type(16)));

union alignas(16) Pack16 { _Float16 h[16]; float4 v[2]; };

static __device__ __forceinline__ void split16(float x, _Float16& hi, _Float16& lo) {
  hi = (_Float16)x;
  lo = (_Float16)(x - (float)hi);
}

// ---------------- Kernel P: MFMA pairwise min ----------------
// grid = 512: blk = db(5b)*16 + rowgroup(4b). block = 256 thr = 4 waves.
// Block owns 128 rows (4 strips of 32) x ALL 2048 cols of one (b,dir).
// d^2 = a.Q + qw + aw with Q=-2q, computed EXACTLY(~2^-22) in ONE
// mfma_f32_32x32x16_f16 via K-slot split:
//   A row slots:  [ah x3][ah x3][al x3][1][1][awh][awl][0 x3]
//   B col slots:  [Qh x3][Ql x3][Qh x3][qwh][qwl][1][1][0 x3]
// Both sides use identical (group,j) slot positions -> k-map invariant.
// LDS frags stored per 16B unit u=2*row+g, XOR-swizzled u^=(row>>2)&1
// (both write and read sides) -> conflict-free ds_read_b128.
// C layout row/col orientation never needed: dir0+dir1 is transpose-symmetric
// and we only ever (min over one axis, then sum over everything).
__global__ __launch_bounds__(256) void pair_mfma_kernel(
    const float* __restrict__ R_t, const float* __restrict__ t_t,
    const float* __restrict__ R_p, const float* __restrict__ t_p,
    const float* __restrict__ mp, float* __restrict__ partial) {
  __shared__ __align__(16) _Float16 Apack[128 * 16];  // 4 KB
  __shared__ __align__(16) _Float16 Bpack[256 * 16];  // 8 KB
  __shared__ float bsum[8];
  int blk = blockIdx.x;
  int t = threadIdx.x;
  int rg = blk & 15;
  int db = blk >> 4;  // 0..31
  int dir = db & 1, b = db >> 1;
  const float* Rr = (dir ? R_p : R_t) + b * 9;
  const float* trv = (dir ? t_p : t_t) + b * 3;
  const float* Rc = (dir ? R_t : R_p) + b * 9;
  const float* tcv = (dir ? t_t : t_p) + b * 3;

  // --- pack this block's 128 rows (A side) ---
  if (t < 128) {
    int ri = (b << 11) + (rg << 7) + t;
    float x = mp[ri * 3], y = mp[ri * 3 + 1], z = mp[ri * 3 + 2];
    float axf = fmaf(Rr[0], x, fmaf(Rr[1], y, fmaf(Rr[2], z, trv[0])));
    float ayf = fmaf(Rr[3], x, fmaf(Rr[4], y, fmaf(Rr[5], z, trv[1])));
    float azf = fmaf(Rr[6], x, fmaf(Rr[7], y, fmaf(Rr[8], z, trv[2])));
    float awf = fmaf(axf, axf, fmaf(ayf, ayf, azf * azf));
    _Float16 hx, lx, hy, ly, hz, lz, hw, lw;
    split16(axf, hx, lx); split16(ayf, hy, ly); split16(azf, hz, lz);
    split16(awf, hw, lw);
    Pack16 pk;
    pk.h[0] = hx;  pk.h[1] = hy;  pk.h[2] = hz;
    pk.h[3] = hx;  pk.h[4] = hy;  pk.h[5] = hz;
    pk.h[6] = lx;  pk.h[7] = ly;  pk.h[8] = lz;
    pk.h[9] = (_Float16)1.0f; pk.h[10] = (_Float16)1.0f;
    pk.h[11] = hw; pk.h[12] = lw;
    pk.h[13] = (_Float16)0.0f; pk.h[14] = (_Float16)0.0f; pk.h[15] = (_Float16)0.0f;
    int xr = (t >> 2) & 1;
    *(float4*)&Apack[(((t << 1) | 0) ^ xr) * 8] = pk.v[0];
    *(float4*)&Apack[(((t << 1) | 1) ^ xr) * 8] = pk.v[1];
  }

  // prefetch chunk 0 col point
  float ncx, ncy, ncz;
  { int ci = (b << 11) + t; ncx = mp[ci * 3]; ncy = mp[ci * 3 + 1]; ncz = mp[ci * 3 + 2]; }

  __syncthreads();

  int lane = t & 63;
  int wv = t >> 6;        // wave -> 32-row strip
  int cl = lane & 31;
  int g = lane >> 5;      // k-group 0/1 (slots g*8..g*8+7)
  int xorb = (cl >> 2) & 1;
  int rl = (wv << 5) + cl;
  const half8 a_frag = *(const half8*)&Apack[((((rl << 1) | g)) ^ xorb) * 8];
  const _Float16* bbase = &Bpack[(((cl << 1) | g) ^ xorb) * 8];

  float m[16];
#pragma unroll
  for (int r = 0; r < 16; ++r) m[r] = 3.0e38f;
  floatx16 zacc = {};

  for (int c = 0; c < 8; ++c) {
    // pack this chunk's col (1/thread) from prefetched regs (B side)
    {
      float qx = fmaf(Rc[0], ncx, fmaf(Rc[1], ncy, fmaf(Rc[2], ncz, tcv[0])));
      float qy = fmaf(Rc[3], ncx, fmaf(Rc[4], ncy, fmaf(Rc[5], ncz, tcv[1])));
      float qz = fmaf(Rc[6], ncx, fmaf(Rc[7], ncy, fmaf(Rc[8], ncz, tcv[2])));
      float qw = fmaf(qx, qx, fmaf(qy, qy, qz * qz));
      float Qx = -2.f * qx, Qy = -2.f * qy, Qz = -2.f * qz;
      _Float16 hx, lx, hy, ly, hz, lz, hw, lw;
      split16(Qx, hx, lx); split16(Qy, hy, ly); split16(Qz, hz, lz);
      split16(qw, hw, lw);
      Pack16 pk;
      pk.h[0] = hx;  pk.h[1] = hy;  pk.h[2] = hz;
      pk.h[3] = lx;  pk.h[4] = ly;  pk.h[5] = lz;
      pk.h[6] = hx;  pk.h[7] = hy;  pk.h[8] = hz;
      pk.h[9] = hw;  pk.h[10] = lw;
      pk.h[11] = (_Float16)1.0f; pk.h[12] = (_Float16)1.0f;
      pk.h[13] = (_Float16)0.0f; pk.h[14] = (_Float16)0.0f; pk.h[15] = (_Float16)0.0f;
      int xr = (t >> 2) & 1;
      *(float4*)&Bpack[(((t << 1) | 0) ^ xr) * 8] = pk.v[0];
      *(float4*)&Bpack[(((t << 1) | 1) ^ xr) * 8] = pk.v[1];
    }
    __syncthreads();  // B ready
    if (c < 7) {      // prefetch next chunk under compute
      int ci = (b << 11) + ((c + 1) << 8) + t;
      ncx = mp[ci * 3]; ncy = mp[ci * 3 + 1]; ncz = mp[ci * 3 + 2];
    }
#pragma unroll
    for (int ct = 0; ct < 8; ct += 2) {
      half8 b0 = *(const half8*)(bbase + ct * 512);        // +1024B/tile, swizzle-consistent
      half8 b1 = *(const half8*)(bbase + (ct + 1) * 512);
      floatx16 acc0 = __builtin_amdgcn_mfma_f32_32x32x16_f16(a_frag, b0, zacc, 0, 0, 0);
      floatx16 acc1 = __builtin_amdgcn_mfma_f32_32x32x16_f16(a_frag, b1, zacc, 0, 0, 0);
#pragma unroll
      for (int r = 0; r < 16; ++r)
        m[r] = fminf(fminf(m[r], acc0[r]), acc1[r]);       // v_min3_f32
    }
    __syncthreads();  // chunk consumed
  }

  // min across the 32 lanes sharing g (bits 0..4) -> per-(hi,reg) row mins
#pragma unroll
  for (int mask = 1; mask <= 16; mask <<= 1)
#pragma unroll
    for (int r = 0; r < 16; ++r) m[r] = fminf(m[r], __shfl_xor(m[r], mask, 64));

  float s = 0.f;
#pragma unroll
  for (int r = 0; r < 16; ++r) s += sqrtf(fmaxf(m[r], 0.f) + EPSF);
  if (cl == 0) bsum[(wv << 1) | g] = s;
  __syncthreads();
  if (t == 0) {
    float tot = 0.f;
#pragma unroll
    for (int i = 0; i < 8; ++i) tot += bsum[i];
    partial[blk] = tot * SCALE;
  }
}

// ---------------- Kernel F: sum 512 block partials ----------------
__global__ __launch_bounds__(256) void finish_kernel(
    const float* __restrict__ partial, float* __restrict__ out) {
  int t = threadIdx.x;
  float v = partial[t] + partial[t + 256];
  for (int off = 32; off; off >>= 1) v += __shfl_down(v, off, 64);
  __shared__ float ws4[4];
  if ((t & 63) == 0) ws4[t >> 6] = v;
  __syncthreads();
  if (t == 0) out[0] = ws4[0] + ws4[1] + ws4[2] + ws4[3];
}

// ---------------- Fallback (tiny ws): self-contained, no scratch ------------
__global__ __launch_bounds__(256) void fallback_kernel(
    const float* __restrict__ R_t, const float* __restrict__ t_t,
    const float* __restrict__ R_p, const float* __restrict__ t_p,
    const float* __restrict__ mp, float* __restrict__ out) {
  __shared__ float4 lds[PP];  // 32 KB
  int blk = blockIdx.x;
  int rc  = blk & 7;
  int dir = (blk >> 3) & 1;
  int b   = blk >> 4;
  const float* Rr = (dir ? R_p : R_t) + b * 9;
  const float* tr_ = (dir ? t_p : t_t) + b * 3;
  const float* Rc = (dir ? R_t : R_p) + b * 9;
  const float* tcp = (dir ? t_t : t_p) + b * 3;
  float c0 = Rc[0], c1 = Rc[1], c2 = Rc[2], c3 = Rc[3], c4 = Rc[4],
        c5 = Rc[5], c6 = Rc[6], c7 = Rc[7], c8 = Rc[8];
  float tc0 = tcp[0], tc1 = tcp[1], tc2 = tcp[2];
  for (int j = threadIdx.x; j < PP; j += 256) {
    int gi = (b * PP + j) * 3;
    float x = mp[gi], y = mp[gi + 1], z = mp[gi + 2];
    float4 q;
    q.x = fmaf(c0, x, fmaf(c1, y, fmaf(c2, z, tc0)));
    q.y = fmaf(c3, x, fmaf(c4, y, fmaf(c5, z, tc1)));
    q.z = fmaf(c6, x, fmaf(c7, y, fmaf(c8, z, tc2)));
    q.w = 0.f;
    lds[j] = q;
  }
  __syncthreads();
  int row = rc * 256 + threadIdx.x;
  int gi = (b * PP + row) * 3;
  float x = mp[gi], y = mp[gi + 1], z = mp[gi + 2];
  float ax = fmaf(Rr[0], x, fmaf(Rr[1], y, fmaf(Rr[2], z, tr_[0])));
  float ay = fmaf(Rr[3], x, fmaf(Rr[4], y, fmaf(Rr[5], z, tr_[1])));
  float az = fmaf(Rr[6], x, fmaf(Rr[7], y, fmaf(Rr[8], z, tr_[2])));
  float m = 3.4e38f;
#pragma unroll 8
  for (int j = 0; j < PP; ++j) {
    float4 q = lds[j];
    float dx = ax - q.x, dy = ay - q.y, dz = az - q.z;
    float d = fmaf(dx, dx, fmaf(dy, dy, dz * dz));
    m = fminf(m, d);
  }
  float v = sqrtf(m + EPSF) * SCALE;
  for (int off = 32; off; off >>= 1) v += __shfl_down(v, off, 64);
  __shared__ float wsum[4];
  if ((threadIdx.x & 63) == 0) wsum[threadIdx.x >> 6] = v;
  __syncthreads();
  if (threadIdx.x == 0) atomicAdd(out, wsum[0] + wsum[1] + wsum[2] + wsum[3]);
}

extern "C" void kernel_launch(void* const* d_in, const int* in_sizes, int n_in,
                              void* d_out, int out_size, void* d_ws, size_t ws_size,
                              hipStream_t stream) {
  const float* R_t = (const float*)d_in[0];
  const float* t_t = (const float*)d_in[1];
  const float* R_p = (const float*)d_in[2];
  const float* t_p = (const float*)d_in[3];
  const float* mp  = (const float*)d_in[4];
  float* out = (float*)d_out;

  if (ws_size >= 512 * sizeof(float)) {
    float* partial = (float*)d_ws;
    pair_mfma_kernel<<<512, 256, 0, stream>>>(R_t, t_t, R_p, t_p, mp, partial);
    finish_kernel<<<1, 256, 0, stream>>>(partial, out);
  } else {
    hipMemsetAsync(d_out, 0, sizeof(float), stream);
    fallback_kernel<<<256, 256, 0, stream>>>(R_t, t_t, R_p, t_p, mp, out);
  }
}